// Round 9
// baseline (48.026 us; speedup 1.0000x reference)
//
#include <hip/hip_runtime.h>
#include <math.h>

#define HD 256
#define SD 768
#define D2 512
#define NE 8
#define NB 32
#define NBLK 256
#define NTHR 256
#define SFP 516   // padded row stride for [32][512] staging

typedef float f32x4 __attribute__((ext_vector_type(4)));
typedef unsigned u32x4 __attribute__((ext_vector_type(4)));

__device__ __forceinline__ float gelu_exact(float x) {
    return 0.5f * x * (1.0f + erff(x * 0.70710678118654752f));
}

// ---- Coherent (L2-bypassing) access for cross-block intermediates ----------
__device__ __forceinline__ void cstf(float* p, float v) {
    __hip_atomic_store(p, v, __ATOMIC_RELAXED, __HIP_MEMORY_SCOPE_AGENT);
}
__device__ __forceinline__ float cldf(const float* p) {
    return __hip_atomic_load(p, __ATOMIC_RELAXED, __HIP_MEMORY_SCOPE_AGENT);
}
__device__ __forceinline__ void csti(int* p, int v) {
    __hip_atomic_store(p, v, __ATOMIC_RELAXED, __HIP_MEMORY_SCOPE_AGENT);
}
__device__ __forceinline__ int cldi(const int* p) {
    return __hip_atomic_load(p, __ATOMIC_RELAXED, __HIP_MEMORY_SCOPE_AGENT);
}
__device__ __forceinline__ f32x4 cld4(const float* p) {
    f32x4 v;
    asm volatile("global_load_dwordx4 %0, %1, off sc0 sc1\n\t"
                 "s_waitcnt vmcnt(0)" : "=&v"(v) : "v"(p) : "memory");
    return v;
}

// Bulk-stage 16KB global->LDS ([32][SFP]), 16 pipelined coherent dwordx4
// loads, one vmcnt drain, LDS float4 writes (R6, verified).
__device__ __forceinline__ void stage16k(const float* __restrict__ gsrc,
                                         float* __restrict__ lds, int t)
{
    const f32x4* src = (const f32x4*)gsrc;
    f32x4 r[16];
    #pragma unroll
    for (int j = 0; j < 16; ++j) {
        const f32x4* p = src + (t + j * 256);
        asm volatile("global_load_dwordx4 %0, %1, off sc0 sc1"
                     : "=v"(r[j]) : "v"(p));
    }
    asm volatile("s_waitcnt vmcnt(0)" ::: "memory");
    __builtin_amdgcn_sched_barrier(0);
    #pragma unroll
    for (int j = 0; j < 16; ++j) {
        int q = t + j * 256;
        *(f32x4*)&lds[(q >> 7) * SFP + (q & 127) * 4] = r[j];
    }
}

// Hierarchical grid barrier (R7, verified).
__device__ __forceinline__ void gsync(unsigned* slots, unsigned* gen,
                                      unsigned tok) {
    __syncthreads();   // drains vmcnt -> this block's sc1 stores are at L3
    const int t = threadIdx.x;
    if (t == 0)
        __hip_atomic_store(slots + blockIdx.x, tok, __ATOMIC_RELAXED,
                           __HIP_MEMORY_SCOPE_AGENT);
    if (blockIdx.x == 0) {
        if (t < 64) {
            const u32x4* p = (const u32x4*)slots + t;
            for (;;) {
                u32x4 v;
                asm volatile("global_load_dwordx4 %0, %1, off sc0 sc1\n\t"
                             "s_waitcnt vmcnt(0)"
                             : "=&v"(v) : "v"(p) : "memory");
                bool ok = (v[0] == tok) & (v[1] == tok) &
                          (v[2] == tok) & (v[3] == tok);
                if (__ballot(ok) == ~0ull) break;
                __builtin_amdgcn_s_sleep(1);
            }
            if (t == 0)
                __hip_atomic_store(gen, tok, __ATOMIC_RELAXED,
                                   __HIP_MEMORY_SCOPE_AGENT);
        }
    } else {
        if (t == 0) {
            while (__hip_atomic_load(gen, __ATOMIC_RELAXED,
                                     __HIP_MEMORY_SCOPE_AGENT) != tok)
                __builtin_amdgcn_s_sleep(1);
        }
    }
    __builtin_amdgcn_fence(__ATOMIC_ACQUIRE, "workgroup");
    __syncthreads();
}

// Shared-memory carve-up (floats)
#define S_F     0                    // 16512 (staging / A & C scratch)
#define S_W     16512                // 8192
#define S_R2    (16512 + 8192)       // 2048 (k-split partials)
#define S_RED   (16512 + 8192 + 2048)        // 256
#define S_SMALL (16512 + 8192 + 2048 + 256)  // 16
#define SMEM_F  (16512 + 8192 + 2048 + 256 + 16)   // 108,096 B

__global__ __launch_bounds__(256) void fused_all(
    const float* __restrict__ smiles,
    const float* __restrict__ sW, const float* __restrict__ sb,
    const float* __restrict__ Wv, const float* __restrict__ bv,
    const float* __restrict__ Wo, const float* __restrict__ bo,
    const float* __restrict__ gW, const float* __restrict__ gb,
    const float* __restrict__ W1, const float* __restrict__ b1,
    const float* __restrict__ W2, const float* __restrict__ b2,
    const float* __restrict__ lng, const float* __restrict__ lnb,
    const float* __restrict__ clsW, const float* __restrict__ clsb,
    float* __restrict__ fused, float* __restrict__ probs,
    float* __restrict__ pn, int* __restrict__ sel,
    float* __restrict__ h1, unsigned* __restrict__ slots,
    unsigned* __restrict__ gen, unsigned* __restrict__ LC,
    float* __restrict__ out)
{
    __shared__ __align__(16) float smem[SMEM_F];
    __shared__ unsigned s_lc;
    const int bid = blockIdx.x, t = threadIdx.x;

    if (t == 0)
        s_lc = __hip_atomic_load(LC, __ATOMIC_RELAXED, __HIP_MEMORY_SCOPE_AGENT);
    __syncthreads();
    const unsigned tb = s_lc * 2654435761u;

    // ===== Phase A (32 blocks, per-row): proj -> v -> att -> gate/top2 =======
    if (bid < NB) {
        int b = bid;
        float* s_in  = smem + S_F;            // 768
        float* s_p   = smem + S_F + 768;      // 256
        float* s_v   = smem + S_F + 1024;     // 256
        float* s_f2  = smem + S_F + 1280;     // 512
        float* s_acc = smem + S_R2;           // 1024
        float* s_red = smem + S_RED;
        float* s_gate = smem + S_SMALL;

        // stage smiles row (768 fl)
        if (t < SD / 4)
            *(f32x4*)&s_in[t * 4] = *(const f32x4*)(smiles + (size_t)b * SD + t * 4);
        __syncthreads();

        int ks = t >> 6, cg = t & 63;

        // proj = smiles_row @ sW + sb  (4 k-splits x 192, wide weight loads)
        {
            f32x4 acc = {0.f, 0.f, 0.f, 0.f};
            #pragma unroll 8
            for (int kk = 0; kk < 192; ++kk) {
                int k = ks * 192 + kk;
                f32x4 w = *(const f32x4*)(sW + (size_t)k * HD + cg * 4);
                acc += s_in[k] * w;
            }
            *(f32x4*)&s_acc[ks * 256 + cg * 4] = acc;
        }
        __syncthreads();
        {
            float p = s_acc[t] + s_acc[256 + t] + s_acc[512 + t] + s_acc[768 + t]
                    + sb[t];
            s_p[t] = p;
            s_f2[HD + t] = p;
            cstf(fused + (size_t)b * 2 * HD + HD + t, p);
        }
        __syncthreads();

        // v = proj @ Wv + bv
        {
            f32x4 av = {0.f, 0.f, 0.f, 0.f};
            #pragma unroll 16
            for (int kk = 0; kk < 64; ++kk) {
                int k = ks * 64 + kk;
                f32x4 w = *(const f32x4*)(Wv + (size_t)k * HD + cg * 4);
                av += s_p[k] * w;
            }
            *(f32x4*)&s_acc[ks * 256 + cg * 4] = av;
        }
        __syncthreads();
        s_v[t] = s_acc[t] + s_acc[256 + t] + s_acc[512 + t] + s_acc[768 + t]
               + bv[t];
        __syncthreads();

        // att = v @ Wo + bo
        {
            f32x4 ao = {0.f, 0.f, 0.f, 0.f};
            #pragma unroll 16
            for (int kk = 0; kk < 64; ++kk) {
                int k = ks * 64 + kk;
                f32x4 w = *(const f32x4*)(Wo + (size_t)k * HD + cg * 4);
                ao += s_v[k] * w;
            }
            *(f32x4*)&s_acc[ks * 256 + cg * 4] = ao;
        }
        __syncthreads();
        {
            float att = s_acc[t] + s_acc[256 + t] + s_acc[512 + t] + s_acc[768 + t]
                      + bo[t];
            s_f2[t] = att;
            cstf(fused + (size_t)b * 2 * HD + t, att);
        }
        __syncthreads();

        // gate logits -> softmax -> top2 (R8, verified)
        int e = t & 7, ch = t >> 3;
        float gp = 0.f;
        #pragma unroll
        for (int j = 0; j < 16; ++j) {
            int d = ch * 16 + j;
            gp = fmaf(s_f2[d], gW[d * NE + e], gp);
        }
        s_red[t] = gp;
        __syncthreads();
        for (int off = 128; off >= 8; off >>= 1) {
            if (t < off) s_red[t] += s_red[t + off];
            __syncthreads();
        }
        if (t < NE) s_gate[t] = s_red[t] + gb[t];
        __syncthreads();
        if (t == 0) {
            float m = s_gate[0];
            for (int i = 1; i < NE; ++i) m = fmaxf(m, s_gate[i]);
            float ex[NE], ssum = 0.f;
            for (int i = 0; i < NE; ++i) { ex[i] = expf(s_gate[i] - m); ssum += ex[i]; }
            float pr[NE];
            for (int i = 0; i < NE; ++i) { pr[i] = ex[i] / ssum; cstf(probs + b * NE + i, pr[i]); }
            int i1 = 0;
            for (int i = 1; i < NE; ++i) if (pr[i] > pr[i1]) i1 = i;
            int i2 = (i1 == 0) ? 1 : 0;
            for (int i = 0; i < NE; ++i) if (i != i1 && pr[i] > pr[i2]) i2 = i;
            float p1 = pr[i1], p2 = pr[i2], s12 = p1 + p2;
            csti(sel + b * 2 + 0, i1);
            csti(sel + b * 2 + 1, i2);
            cstf(pn + b * 2 + 0, p1 / s12);
            cstf(pn + b * 2 + 1, p2 / s12);
        }
    }
    gsync(slots + 0 * NBLK, gen + 0, tb + 1u);

    // ===== Phase B: dense h1 = gelu(fused @ W1[e] + b1[e]) (R8 P2, verified) ==
    {
        int e = bid >> 5, ct = bid & 31;
        float* s_f  = smem + S_F;    // [32][516]
        float* s_w  = smem + S_W;    // [512][16]
        float* s_r2 = smem + S_R2;   // [512 outs][4 ks]
        stage16k(fused, s_f, t);
        {
            const float* Wb = W1 + (size_t)e * D2 * D2 + ct * 16;
            #pragma unroll
            for (int j = 0; j < 8; ++j) {
                int q = t + j * 256;
                int k = q >> 2, c4 = (q & 3) * 4;
                *(float4*)&s_w[k * 16 + c4] =
                    *(const float4*)(Wb + (size_t)k * D2 + c4);
            }
        }
        __syncthreads();
        int ks = t >> 6, l = t & 63;
        int rp = l >> 2, c4g = l & 3;
        int r0 = rp * 2, r1 = r0 + 1;
        const float* fr0 = s_f + r0 * SFP;
        const float* fr1 = s_f + r1 * SFP;
        const float* wb = s_w + c4g * 4;
        f32x4 a0 = {0.f, 0.f, 0.f, 0.f}, a1 = {0.f, 0.f, 0.f, 0.f};
        #pragma unroll 4
        for (int kq = 0; kq < 32; ++kq) {
            int k = ks * 128 + kq * 4;
            f32x4 w0 = *(const f32x4*)&wb[(k + 0) * 16];
            f32x4 w1 = *(const f32x4*)&wb[(k + 1) * 16];
            f32x4 w2 = *(const f32x4*)&wb[(k + 2) * 16];
            f32x4 w3 = *(const f32x4*)&wb[(k + 3) * 16];
            f32x4 f0 = *(const f32x4*)&fr0[k];
            f32x4 f1 = *(const f32x4*)&fr1[k];
            a0 += f0[0] * w0 + f0[1] * w1 + f0[2] * w2 + f0[3] * w3;
            a1 += f1[0] * w0 + f1[1] * w1 + f1[2] * w2 + f1[3] * w3;
        }
        int cl = c4g * 4;
        #pragma unroll
        for (int j = 0; j < 4; ++j) {
            s_r2[(r0 * 16 + cl + j) * 4 + ks] = a0[j];
            s_r2[(r1 * 16 + cl + j) * 4 + ks] = a1[j];
        }
        __syncthreads();
        #pragma unroll
        for (int o = 0; o < 2; ++o) {
            int outi = t * 2 + o;
            f32x4 p = *(const f32x4*)&s_r2[outi * 4];
            int r = outi >> 4, cl2 = outi & 15;
            int col = ct * 16 + cl2;
            float v = p[0] + p[1] + p[2] + p[3] + b1[e * D2 + col];
            cstf(h1 + ((size_t)e * NB + r) * D2 + col, gelu_exact(v));
        }
    }
    gsync(slots + 1 * NBLK, gen + 1, tb + 2u);

    // launch-token bump: safe — every block already read LC before barrier 1
    if (bid == 0 && t == 0)
        __hip_atomic_store(LC, s_lc + 1u, __ATOMIC_RELAXED, __HIP_MEMORY_SCOPE_AGENT);

    // ===== Phase C (32 blocks, per-row): sparse top-2 expert-out GEMV,
    // combine, LayerNorm, classifier; block 0: aux ==========================
    if (bid < NB) {
        int b = bid;
        float* s_h0 = smem + S_F;            // 512 (p0-scaled h1[e0] row)
        float* s_h1 = smem + S_F + 512;      // 512 (p1-scaled h1[e1] row)
        float* s_acc = smem + S_R2;          // 1024
        float* s_red = smem + S_RED;
        float* s_stats = smem + S_SMALL;

        int e0 = cldi(sel + b * 2 + 0), e1 = cldi(sel + b * 2 + 1);
        float p0 = cldf(pn + b * 2 + 0), p1 = cldf(pn + b * 2 + 1);

        // stage the two selected h1 rows (coherent), pre-scaled by p0/p1
        {
            int q = t & 127;
            const float* src = (t < 128)
                ? h1 + ((size_t)e0 * NB + b) * D2 + q * 4
                : h1 + ((size_t)e1 * NB + b) * D2 + q * 4;
            f32x4 v = cld4(src);
            float pp = (t < 128) ? p0 : p1;
            float* dst = (t < 128) ? &s_h0[q * 4] : &s_h1[q * 4];
            v *= pp;
            *(f32x4*)dst = v;
        }
        __syncthreads();

        // moe[col] = (p0*h1row0) @ W2[e0] + (p1*h1row1) @ W2[e1]  (4 k-splits)
        int ks = t >> 6, cg = t & 63;
        const float* Wb0 = W2 + (size_t)e0 * D2 * HD + cg * 4;
        const float* Wb1 = W2 + (size_t)e1 * D2 * HD + cg * 4;
        f32x4 acc = {0.f, 0.f, 0.f, 0.f};
        #pragma unroll 4
        for (int kq = 0; kq < 32; ++kq) {
            int k = ks * 128 + kq * 4;
            f32x4 h = *(const f32x4*)&s_h0[k];
            f32x4 w0 = *(const f32x4*)(Wb0 + (size_t)(k + 0) * HD);
            f32x4 w1 = *(const f32x4*)(Wb0 + (size_t)(k + 1) * HD);
            f32x4 w2 = *(const f32x4*)(Wb0 + (size_t)(k + 2) * HD);
            f32x4 w3 = *(const f32x4*)(Wb0 + (size_t)(k + 3) * HD);
            acc += h[0] * w0 + h[1] * w1 + h[2] * w2 + h[3] * w3;
        }
        #pragma unroll 4
        for (int kq = 0; kq < 32; ++kq) {
            int k = ks * 128 + kq * 4;
            f32x4 h = *(const f32x4*)&s_h1[k];
            f32x4 w0 = *(const f32x4*)(Wb1 + (size_t)(k + 0) * HD);
            f32x4 w1 = *(const f32x4*)(Wb1 + (size_t)(k + 1) * HD);
            f32x4 w2 = *(const f32x4*)(Wb1 + (size_t)(k + 2) * HD);
            f32x4 w3 = *(const f32x4*)(Wb1 + (size_t)(k + 3) * HD);
            acc += h[0] * w0 + h[1] * w1 + h[2] * w2 + h[3] * w3;
        }
        *(f32x4*)&s_acc[ks * 256 + cg * 4] = acc;
        __syncthreads();

        float moe = s_acc[t] + s_acc[256 + t] + s_acc[512 + t] + s_acc[768 + t]
                  + p0 * b2[e0 * HD + t] + p1 * b2[e1 * HD + t];

        // LayerNorm + classifier (R8 P4, verified)
        s_red[t] = moe; __syncthreads();
        for (int off = 128; off > 0; off >>= 1) {
            if (t < off) s_red[t] += s_red[t + off];
            __syncthreads();
        }
        if (t == 0) s_stats[0] = s_red[0] * (1.f / HD);
        __syncthreads();
        float mu = s_stats[0];
        float d = moe - mu;

        s_red[t] = d * d; __syncthreads();
        for (int off = 128; off > 0; off >>= 1) {
            if (t < off) s_red[t] += s_red[t + off];
            __syncthreads();
        }
        if (t == 0) s_stats[1] = s_red[0] * (1.f / HD);
        __syncthreads();

        float xn = d * rsqrtf(s_stats[1] + 1e-5f);
        float y = fmaf(xn, lng[t], lnb[t]);

        s_red[t] = y * clsW[t * 2 + 0]; __syncthreads();
        for (int off = 128; off > 0; off >>= 1) {
            if (t < off) s_red[t] += s_red[t + off];
            __syncthreads();
        }
        if (t == 0) s_stats[2] = s_red[0] + clsb[0];
        __syncthreads();

        s_red[t] = y * clsW[t * 2 + 1]; __syncthreads();
        for (int off = 128; off > 0; off >>= 1) {
            if (t < off) s_red[t] += s_red[t + off];
            __syncthreads();
        }
        if (t == 0) {
            out[b * 2 + 0] = s_stats[2];
            out[b * 2 + 1] = s_red[0] + clsb[1];
        }

        if (bid == 0) {
            __syncthreads();
            s_red[t] = cldf(probs + t);
            __syncthreads();
            for (int off = 128; off >= 8; off >>= 1) {
                if (t < off) s_red[t] += s_red[t + off];
                __syncthreads();
            }
            if (t == 0) {
                float aux = 0.f;
                for (int e = 0; e < NE; ++e) {
                    float u = s_red[e] * (1.f / 32.f);
                    aux += u * logf(0.125f) - logf(u) * 0.125f;
                }
                out[64] = 0.1f * aux;
            }
        }
    }
}

extern "C" void kernel_launch(void* const* d_in, const int* in_sizes, int n_in,
                              void* d_out, int out_size, void* d_ws, size_t ws_size,
                              hipStream_t stream) {
    (void)in_sizes; (void)n_in; (void)out_size; (void)ws_size;
    const float* smiles = (const float*)d_in[2];
    const float* sW  = (const float*)d_in[7];
    const float* sb  = (const float*)d_in[8];
    const float* Wv  = (const float*)d_in[13];
    const float* bv  = (const float*)d_in[14];
    const float* Wo  = (const float*)d_in[15];
    const float* bo  = (const float*)d_in[16];
    const float* gW  = (const float*)d_in[17];
    const float* gb  = (const float*)d_in[18];
    const float* W1  = (const float*)d_in[19];
    const float* b1  = (const float*)d_in[20];
    const float* W2  = (const float*)d_in[21];
    const float* b2  = (const float*)d_in[22];
    const float* lng = (const float*)d_in[23];
    const float* lnb = (const float*)d_in[24];
    const float* cW  = (const float*)d_in[25];
    const float* cb  = (const float*)d_in[26];
    float* out = (float*)d_out;
    float* ws  = (float*)d_ws;

    float*    fused = ws;                      // 16384
    float*    probs = ws + 16384;              // 256
    float*    pn    = ws + 16640;              // 64
    int*      sel   = (int*)(ws + 16704);      // 64
    float*    h1    = ws + 16768;              // 131072
    unsigned* slots = (unsigned*)(ws + 147840);// 2*256 uints
    unsigned* LC    = (unsigned*)(ws + 148352);// 1 uint
    unsigned* gen   = (unsigned*)(ws + 148353);// 2 uints

    fused_all<<<NBLK, NTHR, 0, stream>>>(
        smiles, sW, sb, Wv, bv, Wo, bo, gW, gb, W1, b1, W2, b2,
        lng, lnb, cW, cb,
        fused, probs, pn, sel, h1, slots, gen, LC, out);
}

// Round 10
// 44.006 us; speedup vs baseline: 1.0913x; 1.0913x over previous
//
#include <hip/hip_runtime.h>
#include <math.h>

#define HD 256
#define SD 768
#define D2 512
#define NE 8
#define NB 32
#define NBLK 256
#define NTHR 256
#define SFP 516   // padded row stride for [32][512] staging

typedef float f32x4 __attribute__((ext_vector_type(4)));
typedef unsigned u32x4 __attribute__((ext_vector_type(4)));

__device__ __forceinline__ float gelu_exact(float x) {
    return 0.5f * x * (1.0f + erff(x * 0.70710678118654752f));
}

// ---- Coherent (L2-bypassing) access for cross-block intermediates ----------
__device__ __forceinline__ void cstf(float* p, float v) {
    __hip_atomic_store(p, v, __ATOMIC_RELAXED, __HIP_MEMORY_SCOPE_AGENT);
}
__device__ __forceinline__ float cldf(const float* p) {
    return __hip_atomic_load(p, __ATOMIC_RELAXED, __HIP_MEMORY_SCOPE_AGENT);
}
__device__ __forceinline__ void csti(int* p, int v) {
    __hip_atomic_store(p, v, __ATOMIC_RELAXED, __HIP_MEMORY_SCOPE_AGENT);
}
__device__ __forceinline__ int cldi(const int* p) {
    return __hip_atomic_load(p, __ATOMIC_RELAXED, __HIP_MEMORY_SCOPE_AGENT);
}

// Bulk-stage 16KB global->LDS ([32][SFP]), 16 pipelined coherent dwordx4
// loads, one vmcnt drain, LDS float4 writes (R6, verified).
__device__ __forceinline__ void stage16k(const float* __restrict__ gsrc,
                                         float* __restrict__ lds, int t)
{
    const f32x4* src = (const f32x4*)gsrc;
    f32x4 r[16];
    #pragma unroll
    for (int j = 0; j < 16; ++j) {
        const f32x4* p = src + (t + j * 256);
        asm volatile("global_load_dwordx4 %0, %1, off sc0 sc1"
                     : "=v"(r[j]) : "v"(p));
    }
    asm volatile("s_waitcnt vmcnt(0)" ::: "memory");
    __builtin_amdgcn_sched_barrier(0);
    #pragma unroll
    for (int j = 0; j < 16; ++j) {
        int q = t + j * 256;
        *(f32x4*)&lds[(q >> 7) * SFP + (q & 127) * 4] = r[j];
    }
}

// ---- DAG sync primitives (R10): producer-subset waits instead of full
// grid barriers. post_slot: __syncthreads drains each thread's vmcnt (sc1
// data stores complete at L3) then thread0 publishes. wait_slots: wave 0
// polls nq quads of the producer slot array (per-lane divergence; each lane
// exits when its quad matches), then block-wide fence+sync.
__device__ __forceinline__ void post_slot(unsigned* slots, unsigned tok) {
    __syncthreads();
    if (threadIdx.x == 0)
        __hip_atomic_store(slots + blockIdx.x, tok, __ATOMIC_RELAXED,
                           __HIP_MEMORY_SCOPE_AGENT);
}

__device__ __forceinline__ void wait_slots(const unsigned* slots, int nq,
                                           unsigned tok) {
    if (threadIdx.x < 64 && (int)threadIdx.x < nq) {
        const u32x4* p = (const u32x4*)slots + threadIdx.x;
        for (;;) {
            u32x4 v;
            asm volatile("global_load_dwordx4 %0, %1, off sc0 sc1\n\t"
                         "s_waitcnt vmcnt(0)"
                         : "=&v"(v) : "v"(p) : "memory");
            if ((v[0] == tok) & (v[1] == tok) & (v[2] == tok) & (v[3] == tok))
                break;
            __builtin_amdgcn_s_sleep(2);
        }
    }
    __builtin_amdgcn_fence(__ATOMIC_ACQUIRE, "workgroup");
    __syncthreads();
}

// Shared-memory carve-up (floats) — R8 layout
#define S_F     0                    // 16512
#define S_W     16512                // 8192
#define S_R2    (16512 + 8192)       // 2048
#define S_RED   (16512 + 8192 + 2048)        // 256
#define S_SMALL (16512 + 8192 + 2048 + 256)  // 16
#define SMEM_F  (16512 + 8192 + 2048 + 256 + 16)

__global__ __launch_bounds__(256) void fused_all(
    const float* __restrict__ smiles,
    const float* __restrict__ sW, const float* __restrict__ sb,
    const float* __restrict__ Wv, const float* __restrict__ bv,
    const float* __restrict__ Wo, const float* __restrict__ bo,
    const float* __restrict__ gW, const float* __restrict__ gb,
    const float* __restrict__ W1, const float* __restrict__ b1,
    const float* __restrict__ W2, const float* __restrict__ b2,
    const float* __restrict__ lng, const float* __restrict__ lnb,
    const float* __restrict__ clsW, const float* __restrict__ clsb,
    float* __restrict__ proj, float* __restrict__ fused,
    float* __restrict__ probs, float* __restrict__ pn,
    int* __restrict__ sel, float* __restrict__ h1,
    float* __restrict__ eo,
    unsigned* __restrict__ slot0, unsigned* __restrict__ slot1,
    unsigned* __restrict__ slot2, unsigned* __restrict__ slot3,
    unsigned* __restrict__ LC, float* __restrict__ out)
{
    __shared__ __align__(16) float smem[SMEM_F];
    __shared__ unsigned s_lc;
    const int bid = blockIdx.x, t = threadIdx.x;

    if (t == 0)
        s_lc = __hip_atomic_load(LC, __ATOMIC_RELAXED, __HIP_MEMORY_SCOPE_AGENT);
    __syncthreads();
    const unsigned tb = s_lc * 2654435761u;

    // ---------------- P0: proj = smiles @ sW + sb (256 blocks) ----------------
    {
        int r = bid >> 3, sl = bid & 7;
        float* s_in = smem + S_F;                   // 768
        float* s_red = smem + S_RED;
        const float* srow = smiles + (size_t)r * SD;
        for (int i = t; i < SD / 4; i += NTHR)
            ((float4*)s_in)[i] = ((const float4*)srow)[i];
        __syncthreads();
        int c = t & 31, kq = t >> 5;                // 32 cols x 8 k-quadrants
        float acc = 0.f;
        const float* wp = sW + (size_t)(kq * 96) * HD + sl * 32 + c;
        #pragma unroll 8
        for (int k = 0; k < 96; ++k)
            acc = fmaf(s_in[kq * 96 + k], wp[(size_t)k * HD], acc);
        s_red[t] = acc;
        __syncthreads();
        if (t < 32) {
            float s = 0.f;
            #pragma unroll
            for (int q = 0; q < 8; ++q) s += s_red[q * 32 + t];
            int col = sl * 32 + t;
            s += sb[col];
            cstf(proj + r * HD + col, s);
            cstf(fused + (size_t)r * 2 * HD + HD + col, s);   // 2nd half = proj
        }
    }
    post_slot(slot0, tb + 1u);

    // ---------------- P1: v -> attended -> gate/top2 (32 blocks) --------------
    if (bid < NB) {
        wait_slots(slot0 + bid * 8, 2, tb + 1u);   // this row's 8 P0 producers
        int b = bid;
        float* s_p   = smem + S_F;           // 256
        float* s_v   = smem + S_F + 256;     // 256
        float* s_f2  = smem + S_F + 512;     // 512
        float* s_acc = smem + S_R2;          // 1024
        float* s_red = smem + S_RED;
        float* s_gate = smem + S_SMALL;
        s_p[t] = cldf(proj + b * HD + t);
        __syncthreads();
        int ks = t >> 6, cg = t & 63;        // 4 k-splits x 64 col-quads

        f32x4 av = {0.f, 0.f, 0.f, 0.f};
        #pragma unroll 16
        for (int kk = 0; kk < 64; ++kk) {
            int k = ks * 64 + kk;
            f32x4 w = *(const f32x4*)(Wv + (size_t)k * HD + cg * 4);
            av += s_p[k] * w;
        }
        *(f32x4*)&s_acc[ks * 256 + cg * 4] = av;
        __syncthreads();
        s_v[t] = s_acc[t] + s_acc[256 + t] + s_acc[512 + t] + s_acc[768 + t]
               + bv[t];
        __syncthreads();

        f32x4 ao = {0.f, 0.f, 0.f, 0.f};
        #pragma unroll 16
        for (int kk = 0; kk < 64; ++kk) {
            int k = ks * 64 + kk;
            f32x4 w = *(const f32x4*)(Wo + (size_t)k * HD + cg * 4);
            ao += s_v[k] * w;
        }
        *(f32x4*)&s_acc[ks * 256 + cg * 4] = ao;
        __syncthreads();
        float att = s_acc[t] + s_acc[256 + t] + s_acc[512 + t] + s_acc[768 + t]
                  + bo[t];
        s_f2[t] = att;
        s_f2[HD + t] = s_p[t];
        cstf(fused + (size_t)b * 2 * HD + t, att);
        __syncthreads();

        int e = t & 7, ch = t >> 3;
        float gp = 0.f;
        #pragma unroll
        for (int j = 0; j < 16; ++j) {
            int d = ch * 16 + j;
            gp = fmaf(s_f2[d], gW[d * NE + e], gp);
        }
        s_red[t] = gp;
        __syncthreads();
        for (int off = 128; off >= 8; off >>= 1) {
            if (t < off) s_red[t] += s_red[t + off];
            __syncthreads();
        }
        if (t < NE) s_gate[t] = s_red[t] + gb[t];
        __syncthreads();
        if (t == 0) {
            float m = s_gate[0];
            for (int i = 1; i < NE; ++i) m = fmaxf(m, s_gate[i]);
            float ex[NE], ssum = 0.f;
            for (int i = 0; i < NE; ++i) { ex[i] = expf(s_gate[i] - m); ssum += ex[i]; }
            float pr[NE];
            for (int i = 0; i < NE; ++i) { pr[i] = ex[i] / ssum; cstf(probs + b * NE + i, pr[i]); }
            int i1 = 0;
            for (int i = 1; i < NE; ++i) if (pr[i] > pr[i1]) i1 = i;
            int i2 = (i1 == 0) ? 1 : 0;
            for (int i = 0; i < NE; ++i) if (i != i1 && pr[i] > pr[i2]) i2 = i;
            float p1 = pr[i1], p2 = pr[i2], s12 = p1 + p2;
            csti(sel + b * 2 + 0, i1);
            csti(sel + b * 2 + 1, i2);
            cstf(pn + b * 2 + 0, p1 / s12);
            cstf(pn + b * 2 + 1, p2 / s12);
        }
        post_slot(slot1, tb + 2u);
    }

    // ------- P2: h1 = gelu(fused @ W1[e] + b1[e]) (256 blocks, reg-tiled) -----
    wait_slots(slot1, 8, tb + 2u);   // all 32 P1 rows
    {
        int e = bid >> 5, ct = bid & 31;
        float* s_f  = smem + S_F;    // [32][516]
        float* s_w  = smem + S_W;    // [512][16]
        float* s_r2 = smem + S_R2;   // [512 outs][4 ks]
        stage16k(fused, s_f, t);
        {
            const float* Wb = W1 + (size_t)e * D2 * D2 + ct * 16;
            #pragma unroll
            for (int j = 0; j < 8; ++j) {
                int q = t + j * 256;
                int k = q >> 2, c4 = (q & 3) * 4;
                *(float4*)&s_w[k * 16 + c4] =
                    *(const float4*)(Wb + (size_t)k * D2 + c4);
            }
        }
        __syncthreads();
        int ks = t >> 6, l = t & 63;
        int rp = l >> 2, c4g = l & 3;
        int r0 = rp * 2, r1 = r0 + 1;
        const float* fr0 = s_f + r0 * SFP;
        const float* fr1 = s_f + r1 * SFP;
        const float* wb = s_w + c4g * 4;
        f32x4 a0 = {0.f, 0.f, 0.f, 0.f}, a1 = {0.f, 0.f, 0.f, 0.f};
        #pragma unroll 4
        for (int kq = 0; kq < 32; ++kq) {
            int k = ks * 128 + kq * 4;
            f32x4 w0 = *(const f32x4*)&wb[(k + 0) * 16];
            f32x4 w1 = *(const f32x4*)&wb[(k + 1) * 16];
            f32x4 w2 = *(const f32x4*)&wb[(k + 2) * 16];
            f32x4 w3 = *(const f32x4*)&wb[(k + 3) * 16];
            f32x4 f0 = *(const f32x4*)&fr0[k];
            f32x4 f1 = *(const f32x4*)&fr1[k];
            a0 += f0[0] * w0 + f0[1] * w1 + f0[2] * w2 + f0[3] * w3;
            a1 += f1[0] * w0 + f1[1] * w1 + f1[2] * w2 + f1[3] * w3;
        }
        int cl = c4g * 4;
        #pragma unroll
        for (int j = 0; j < 4; ++j) {
            s_r2[(r0 * 16 + cl + j) * 4 + ks] = a0[j];
            s_r2[(r1 * 16 + cl + j) * 4 + ks] = a1[j];
        }
        __syncthreads();
        #pragma unroll
        for (int o = 0; o < 2; ++o) {
            int outi = t * 2 + o;
            f32x4 p = *(const f32x4*)&s_r2[outi * 4];
            int r = outi >> 4, cl2 = outi & 15;
            int col = ct * 16 + cl2;
            float v = p[0] + p[1] + p[2] + p[3] + b1[e * D2 + col];
            cstf(h1 + ((size_t)e * NB + r) * D2 + col, gelu_exact(v));
        }
    }
    post_slot(slot2, tb + 3u);
    if (bid >= 128) return;          // no further work for these blocks

    // ------- P3: eo = h1 @ W2[e] + b2[e] (128 blocks, reg-tiled) --------------
    {
        int e = bid >> 4, ct = bid & 15;
        wait_slots(slot2 + e * 32, 8, tb + 3u);   // this expert's 32 producers
        float* s_h  = smem + S_F;
        float* s_w  = smem + S_W;
        float* s_r2 = smem + S_R2;
        stage16k(h1 + (size_t)e * NB * D2, s_h, t);
        {
            const float* Wb = W2 + (size_t)e * D2 * HD + ct * 16;
            #pragma unroll
            for (int j = 0; j < 8; ++j) {
                int q = t + j * 256;
                int k = q >> 2, c4 = (q & 3) * 4;
                *(float4*)&s_w[k * 16 + c4] =
                    *(const float4*)(Wb + (size_t)k * HD + c4);
            }
        }
        __syncthreads();
        int ks = t >> 6, l = t & 63;
        int rp = l >> 2, c4g = l & 3;
        int r0 = rp * 2, r1 = r0 + 1;
        const float* fr0 = s_h + r0 * SFP;
        const float* fr1 = s_h + r1 * SFP;
        const float* wb = s_w + c4g * 4;
        f32x4 a0 = {0.f, 0.f, 0.f, 0.f}, a1 = {0.f, 0.f, 0.f, 0.f};
        #pragma unroll 4
        for (int kq = 0; kq < 32; ++kq) {
            int k = ks * 128 + kq * 4;
            f32x4 w0 = *(const f32x4*)&wb[(k + 0) * 16];
            f32x4 w1 = *(const f32x4*)&wb[(k + 1) * 16];
            f32x4 w2 = *(const f32x4*)&wb[(k + 2) * 16];
            f32x4 w3 = *(const f32x4*)&wb[(k + 3) * 16];
            f32x4 f0 = *(const f32x4*)&fr0[k];
            f32x4 f1 = *(const f32x4*)&fr1[k];
            a0 += f0[0] * w0 + f0[1] * w1 + f0[2] * w2 + f0[3] * w3;
            a1 += f1[0] * w0 + f1[1] * w1 + f1[2] * w2 + f1[3] * w3;
        }
        int cl = c4g * 4;
        #pragma unroll
        for (int j = 0; j < 4; ++j) {
            s_r2[(r0 * 16 + cl + j) * 4 + ks] = a0[j];
            s_r2[(r1 * 16 + cl + j) * 4 + ks] = a1[j];
        }
        __syncthreads();
        #pragma unroll
        for (int o = 0; o < 2; ++o) {
            int outi = t * 2 + o;
            f32x4 p = *(const f32x4*)&s_r2[outi * 4];
            int r = outi >> 4, cl2 = outi & 15;
            int col = ct * 16 + cl2;
            float v = p[0] + p[1] + p[2] + p[3] + b2[e * HD + col];
            cstf(eo + ((size_t)e * NB + r) * HD + col, v);
        }
    }
    post_slot(slot3, tb + 4u);
    if (bid >= NB) return;           // only 32 blocks do P4

    // ---------------- P4: gather/combine, LN, classifier, aux (32 blocks) -----
    wait_slots(slot3, 32, tb + 4u);  // all 128 P3 producers
    {
        int b = bid;
        float* s_red = smem + S_RED;
        float* s_stats = smem + S_SMALL;
        int e0 = cldi(sel + b * 2 + 0), e1 = cldi(sel + b * 2 + 1);
        float p0 = cldf(pn + b * 2 + 0), p1 = cldf(pn + b * 2 + 1);
        float moe = p0 * cldf(eo + ((size_t)e0 * NB + b) * HD + t)
                  + p1 * cldf(eo + ((size_t)e1 * NB + b) * HD + t);

        s_red[t] = moe; __syncthreads();
        for (int off = 128; off > 0; off >>= 1) {
            if (t < off) s_red[t] += s_red[t + off];
            __syncthreads();
        }
        if (t == 0) s_stats[0] = s_red[0] * (1.f / HD);
        __syncthreads();
        float mu = s_stats[0];
        float d = moe - mu;

        s_red[t] = d * d; __syncthreads();
        for (int off = 128; off > 0; off >>= 1) {
            if (t < off) s_red[t] += s_red[t + off];
            __syncthreads();
        }
        if (t == 0) s_stats[1] = s_red[0] * (1.f / HD);
        __syncthreads();

        float xn = d * rsqrtf(s_stats[1] + 1e-5f);
        float y = fmaf(xn, lng[t], lnb[t]);

        s_red[t] = y * clsW[t * 2 + 0]; __syncthreads();
        for (int off = 128; off > 0; off >>= 1) {
            if (t < off) s_red[t] += s_red[t + off];
            __syncthreads();
        }
        if (t == 0) s_stats[2] = s_red[0] + clsb[0];
        __syncthreads();

        s_red[t] = y * clsW[t * 2 + 1]; __syncthreads();
        for (int off = 128; off > 0; off >>= 1) {
            if (t < off) s_red[t] += s_red[t + off];
            __syncthreads();
        }
        if (t == 0) {
            out[b * 2 + 0] = s_stats[2];
            out[b * 2 + 1] = s_red[0] + clsb[1];
        }

        if (bid == 0) {
            __syncthreads();
            s_red[t] = cldf(probs + t);
            __syncthreads();
            for (int off = 128; off >= 8; off >>= 1) {
                if (t < off) s_red[t] += s_red[t + off];
                __syncthreads();
            }
            if (t == 0) {
                float aux = 0.f;
                for (int e = 0; e < NE; ++e) {
                    float u = s_red[e] * (1.f / 32.f);
                    aux += u * logf(0.125f) - logf(u) * 0.125f;
                }
                out[64] = 0.1f * aux;
            }
        }
    }

    // LC bump: block 0 first verifies every block passed its LC read (slot0
    // fully written — instant by now), making the bump race-free.
    if (bid == 0) {
        wait_slots(slot0, 64, tb + 1u);
        if (t == 0)
            __hip_atomic_store(LC, s_lc + 1u, __ATOMIC_RELAXED,
                               __HIP_MEMORY_SCOPE_AGENT);
    }
}

extern "C" void kernel_launch(void* const* d_in, const int* in_sizes, int n_in,
                              void* d_out, int out_size, void* d_ws, size_t ws_size,
                              hipStream_t stream) {
    (void)in_sizes; (void)n_in; (void)out_size; (void)ws_size;
    const float* smiles = (const float*)d_in[2];
    const float* sW  = (const float*)d_in[7];
    const float* sb  = (const float*)d_in[8];
    const float* Wv  = (const float*)d_in[13];
    const float* bv  = (const float*)d_in[14];
    const float* Wo  = (const float*)d_in[15];
    const float* bo  = (const float*)d_in[16];
    const float* gW  = (const float*)d_in[17];
    const float* gb  = (const float*)d_in[18];
    const float* W1  = (const float*)d_in[19];
    const float* b1  = (const float*)d_in[20];
    const float* W2  = (const float*)d_in[21];
    const float* b2  = (const float*)d_in[22];
    const float* lng = (const float*)d_in[23];
    const float* lnb = (const float*)d_in[24];
    const float* cW  = (const float*)d_in[25];
    const float* cb  = (const float*)d_in[26];
    float* out = (float*)d_out;
    float* ws  = (float*)d_ws;

    float*    proj  = ws;                      // 8192
    float*    fused = ws + 8192;               // 16384
    float*    probs = ws + 24576;              // 256
    float*    pn    = ws + 24832;              // 64
    int*      sel   = (int*)(ws + 24896);      // 64
    float*    h1    = ws + 24960;              // 131072
    float*    eo    = ws + 156032;             // 65536
    unsigned* slot0 = (unsigned*)(ws + 221568);// 256
    unsigned* slot1 = (unsigned*)(ws + 221824);// 32 (padded to 64)
    unsigned* slot2 = (unsigned*)(ws + 221888);// 256
    unsigned* slot3 = (unsigned*)(ws + 222144);// 128
    unsigned* LC    = (unsigned*)(ws + 222272);// 1

    fused_all<<<NBLK, NTHR, 0, stream>>>(
        smiles, sW, sb, Wv, bv, Wo, bo, gW, gb, W1, b1, W2, b2,
        lng, lnb, cW, cb,
        proj, fused, probs, pn, sel, h1, eo,
        slot0, slot1, slot2, slot3, LC, out);
}

// Round 11
// 38.819 us; speedup vs baseline: 1.2372x; 1.1336x over previous
//
#include <hip/hip_runtime.h>
#include <math.h>

#define HD 256
#define SD 768
#define D2 512
#define NE 8
#define NB 32
#define NBLK 256
#define NTHR 256
#define SFP 516   // padded row stride for [32][512] staging

typedef float f32x4 __attribute__((ext_vector_type(4)));
typedef unsigned u32x4 __attribute__((ext_vector_type(4)));

__device__ __forceinline__ float gelu_exact(float x) {
    return 0.5f * x * (1.0f + erff(x * 0.70710678118654752f));
}

// ---- Coherent (L2-bypassing) access for cross-block intermediates ----------
__device__ __forceinline__ void cstf(float* p, float v) {
    __hip_atomic_store(p, v, __ATOMIC_RELAXED, __HIP_MEMORY_SCOPE_AGENT);
}
__device__ __forceinline__ float cldf(const float* p) {
    return __hip_atomic_load(p, __ATOMIC_RELAXED, __HIP_MEMORY_SCOPE_AGENT);
}
__device__ __forceinline__ void csti(int* p, int v) {
    __hip_atomic_store(p, v, __ATOMIC_RELAXED, __HIP_MEMORY_SCOPE_AGENT);
}
__device__ __forceinline__ int cldi(const int* p) {
    return __hip_atomic_load(p, __ATOMIC_RELAXED, __HIP_MEMORY_SCOPE_AGENT);
}

// Bulk-stage 16KB global->LDS ([32][SFP]), 16 pipelined coherent dwordx4
// loads, one vmcnt drain, LDS float4 writes (R6, verified).
__device__ __forceinline__ void stage16k(const float* __restrict__ gsrc,
                                         float* __restrict__ lds, int t)
{
    const f32x4* src = (const f32x4*)gsrc;
    f32x4 r[16];
    #pragma unroll
    for (int j = 0; j < 16; ++j) {
        const f32x4* p = src + (t + j * 256);
        asm volatile("global_load_dwordx4 %0, %1, off sc0 sc1"
                     : "=v"(r[j]) : "v"(p));
    }
    asm volatile("s_waitcnt vmcnt(0)" ::: "memory");
    __builtin_amdgcn_sched_barrier(0);
    #pragma unroll
    for (int j = 0; j < 16; ++j) {
        int q = t + j * 256;
        *(f32x4*)&lds[(q >> 7) * SFP + (q & 127) * 4] = r[j];
    }
}

// ---- Sync (R8-style hierarchical, split into post / finish so weight
// prefetch can overlap the detect round). Small-waiter subset wait for P0->P1.
__device__ __forceinline__ void post_slot(unsigned* slots, unsigned tok) {
    __syncthreads();   // drains vmcnt -> this block's sc1 stores are at L3
    if (threadIdx.x == 0)
        __hip_atomic_store(slots + blockIdx.x, tok, __ATOMIC_RELAXED,
                           __HIP_MEMORY_SCOPE_AGENT);
}

__device__ __forceinline__ void finish_full(const unsigned* slots,
                                            unsigned* gen, unsigned tok) {
    const int t = threadIdx.x;
    if (blockIdx.x == 0) {
        if (t < 64) {
            const u32x4* p = (const u32x4*)slots + t;
            for (;;) {
                u32x4 v;
                asm volatile("global_load_dwordx4 %0, %1, off sc0 sc1\n\t"
                             "s_waitcnt vmcnt(0)"
                             : "=&v"(v) : "v"(p) : "memory");
                bool ok = (v[0] == tok) & (v[1] == tok) &
                          (v[2] == tok) & (v[3] == tok);
                if (__ballot(ok) == ~0ull) break;
                __builtin_amdgcn_s_sleep(1);
            }
            if (t == 0)
                __hip_atomic_store(gen, tok, __ATOMIC_RELAXED,
                                   __HIP_MEMORY_SCOPE_AGENT);
        }
    } else {
        if (t == 0) {
            while (__hip_atomic_load(gen, __ATOMIC_RELAXED,
                                     __HIP_MEMORY_SCOPE_AGENT) != tok)
                __builtin_amdgcn_s_sleep(1);
        }
    }
    __builtin_amdgcn_fence(__ATOMIC_ACQUIRE, "workgroup");
    __syncthreads();
}

__device__ __forceinline__ void wait_subset(const unsigned* slots, int nq,
                                            unsigned tok) {
    if ((int)threadIdx.x < nq) {
        const u32x4* p = (const u32x4*)slots + threadIdx.x;
        for (;;) {
            u32x4 v;
            asm volatile("global_load_dwordx4 %0, %1, off sc0 sc1\n\t"
                         "s_waitcnt vmcnt(0)"
                         : "=&v"(v) : "v"(p) : "memory");
            if ((v[0] == tok) & (v[1] == tok) & (v[2] == tok) & (v[3] == tok))
                break;
            __builtin_amdgcn_s_sleep(2);
        }
    }
    __builtin_amdgcn_fence(__ATOMIC_ACQUIRE, "workgroup");
    __syncthreads();
}

// Shared-memory carve-up (floats)
#define S_F     0                    // 32*516 = 16512
#define S_W     16512                // 512*16 = 8192
#define S_R2    (16512 + 8192)       // 8*512 = 4096 (k-split partials; P1 s_acc)
#define S_RED   (16512 + 8192 + 4096)        // 256
#define S_SMALL (16512 + 8192 + 4096 + 256)  // 16
#define SMEM_F  (16512 + 8192 + 4096 + 256 + 16)   // 116,288 B

__global__ __launch_bounds__(256) void fused_all(
    const float* __restrict__ smiles,
    const float* __restrict__ sW, const float* __restrict__ sb,
    const float* __restrict__ Wv, const float* __restrict__ bv,
    const float* __restrict__ Wo, const float* __restrict__ bo,
    const float* __restrict__ gW, const float* __restrict__ gb,
    const float* __restrict__ W1, const float* __restrict__ b1,
    const float* __restrict__ W2, const float* __restrict__ b2,
    const float* __restrict__ lng, const float* __restrict__ lnb,
    const float* __restrict__ clsW, const float* __restrict__ clsb,
    float* __restrict__ proj, float* __restrict__ fused,
    float* __restrict__ probs, float* __restrict__ pn,
    int* __restrict__ sel, float* __restrict__ h1,
    float* __restrict__ eo,
    unsigned* __restrict__ slot0, unsigned* __restrict__ slot1,
    unsigned* __restrict__ slot2, unsigned* __restrict__ slot3,
    unsigned* __restrict__ gen, unsigned* __restrict__ LC,
    float* __restrict__ out)
{
    __shared__ __align__(16) float smem[SMEM_F];
    __shared__ unsigned s_lc;
    const int bid = blockIdx.x, t = threadIdx.x;

    if (t == 0)
        s_lc = __hip_atomic_load(LC, __ATOMIC_RELAXED, __HIP_MEMORY_SCOPE_AGENT);
    __syncthreads();
    const unsigned tb = s_lc * 2654435761u;

    // ---------------- P0: proj = smiles @ sW + sb (256 blocks) ----------------
    {
        int r = bid >> 3, sl = bid & 7;
        float* s_in = smem + S_F;                   // 768
        float* s_red = smem + S_RED;
        const float* srow = smiles + (size_t)r * SD;
        for (int i = t; i < SD / 4; i += NTHR)
            ((float4*)s_in)[i] = ((const float4*)srow)[i];
        __syncthreads();
        int c = t & 31, kq = t >> 5;                // 32 cols x 8 k-quadrants
        float acc = 0.f;
        const float* wp = sW + (size_t)(kq * 96) * HD + sl * 32 + c;
        #pragma unroll 8
        for (int k = 0; k < 96; ++k)
            acc = fmaf(s_in[kq * 96 + k], wp[(size_t)k * HD], acc);
        s_red[t] = acc;
        __syncthreads();
        if (t < 32) {
            float s = 0.f;
            #pragma unroll
            for (int q = 0; q < 8; ++q) s += s_red[q * 32 + t];
            int col = sl * 32 + t;
            s += sb[col];
            cstf(proj + r * HD + col, s);
            cstf(fused + (size_t)r * 2 * HD + HD + col, s);   // 2nd half = proj
        }
    }
    post_slot(slot0, tb + 1u);

    // ---------------- P1: v -> attended -> gate/top2 (32 blocks) --------------
    if (bid < NB) {
        wait_subset(slot0 + bid * 8, 2, tb + 1u);   // this row's 8 P0 producers
        int b = bid;
        float* s_p   = smem + S_F;           // 256
        float* s_v   = smem + S_F + 256;     // 256
        float* s_f2  = smem + S_F + 512;     // 512
        float* s_acc = smem + S_R2;          // 1024
        float* s_red = smem + S_RED;
        float* s_gate = smem + S_SMALL;
        s_p[t] = cldf(proj + b * HD + t);
        __syncthreads();
        int ks = t >> 6, cg = t & 63;        // 4 k-splits x 64 col-quads

        f32x4 av = {0.f, 0.f, 0.f, 0.f};
        #pragma unroll 16
        for (int kk = 0; kk < 64; ++kk) {
            int k = ks * 64 + kk;
            f32x4 w = *(const f32x4*)(Wv + (size_t)k * HD + cg * 4);
            av += s_p[k] * w;
        }
        *(f32x4*)&s_acc[ks * 256 + cg * 4] = av;
        __syncthreads();
        s_v[t] = s_acc[t] + s_acc[256 + t] + s_acc[512 + t] + s_acc[768 + t]
               + bv[t];
        __syncthreads();

        f32x4 ao = {0.f, 0.f, 0.f, 0.f};
        #pragma unroll 16
        for (int kk = 0; kk < 64; ++kk) {
            int k = ks * 64 + kk;
            f32x4 w = *(const f32x4*)(Wo + (size_t)k * HD + cg * 4);
            ao += s_v[k] * w;
        }
        *(f32x4*)&s_acc[ks * 256 + cg * 4] = ao;
        __syncthreads();
        float att = s_acc[t] + s_acc[256 + t] + s_acc[512 + t] + s_acc[768 + t]
                  + bo[t];
        s_f2[t] = att;
        s_f2[HD + t] = s_p[t];
        cstf(fused + (size_t)b * 2 * HD + t, att);
        __syncthreads();

        int e = t & 7, ch = t >> 3;
        float gp = 0.f;
        #pragma unroll
        for (int j = 0; j < 16; ++j) {
            int d = ch * 16 + j;
            gp = fmaf(s_f2[d], gW[d * NE + e], gp);
        }
        s_red[t] = gp;
        __syncthreads();
        for (int off = 128; off >= 8; off >>= 1) {
            if (t < off) s_red[t] += s_red[t + off];
            __syncthreads();
        }
        if (t < NE) s_gate[t] = s_red[t] + gb[t];
        __syncthreads();
        if (t == 0) {
            float m = s_gate[0];
            for (int i = 1; i < NE; ++i) m = fmaxf(m, s_gate[i]);
            float ex[NE], ssum = 0.f;
            for (int i = 0; i < NE; ++i) { ex[i] = expf(s_gate[i] - m); ssum += ex[i]; }
            float pr[NE];
            for (int i = 0; i < NE; ++i) { pr[i] = ex[i] / ssum; cstf(probs + b * NE + i, pr[i]); }
            int i1 = 0;
            for (int i = 1; i < NE; ++i) if (pr[i] > pr[i1]) i1 = i;
            int i2 = (i1 == 0) ? 1 : 0;
            for (int i = 0; i < NE; ++i) if (i != i1 && pr[i] > pr[i2]) i2 = i;
            float p1 = pr[i1], p2 = pr[i2], s12 = p1 + p2;
            csti(sel + b * 2 + 0, i1);
            csti(sel + b * 2 + 1, i2);
            cstf(pn + b * 2 + 0, p1 / s12);
            cstf(pn + b * 2 + 1, p2 / s12);
        }
    }
    post_slot(slot1, tb + 2u);

    // prefetch this block's W1 tile into LDS during the barrier window
    {
        int e = bid >> 5, ct = bid & 31;
        float* s_w = smem + S_W;
        const float* Wb = W1 + (size_t)e * D2 * D2 + ct * 16;
        #pragma unroll
        for (int j = 0; j < 8; ++j) {
            int q = t + j * 256;
            int k = q >> 2, c4 = (q & 3) * 4;
            *(float4*)&s_w[k * 16 + c4] = *(const float4*)(Wb + (size_t)k * D2 + c4);
        }
    }
    finish_full(slot1, gen + 0, tb + 2u);

    // ------- P2: h1 = gelu(fused @ W1[e] + b1[e]) (ks=8, 4r x 4c tile) --------
    {
        int e = bid >> 5, ct = bid & 31;
        float* s_f  = smem + S_F;
        float* s_w  = smem + S_W;
        float* s_r2 = smem + S_R2;   // [8 ks][512 outs]
        stage16k(fused, s_f, t);
        __syncthreads();
        int ks = t >> 5, l = t & 31;
        int rg = l >> 2, c4g = l & 3;
        const float* wb = s_w + c4g * 4;
        int k0 = ks * 64;
        f32x4 a0 = {0.f,0.f,0.f,0.f}, a1 = a0, a2 = a0, a3 = a0;
        #pragma unroll 2
        for (int kq = 0; kq < 16; ++kq) {
            int k = k0 + kq * 4;
            f32x4 w0 = *(const f32x4*)&wb[(k + 0) * 16];
            f32x4 w1 = *(const f32x4*)&wb[(k + 1) * 16];
            f32x4 w2 = *(const f32x4*)&wb[(k + 2) * 16];
            f32x4 w3 = *(const f32x4*)&wb[(k + 3) * 16];
            f32x4 f0 = *(const f32x4*)&s_f[(rg     ) * SFP + k];
            f32x4 f1 = *(const f32x4*)&s_f[(rg +  8) * SFP + k];
            f32x4 f2 = *(const f32x4*)&s_f[(rg + 16) * SFP + k];
            f32x4 f3 = *(const f32x4*)&s_f[(rg + 24) * SFP + k];
            a0 += f0[0]*w0 + f0[1]*w1 + f0[2]*w2 + f0[3]*w3;
            a1 += f1[0]*w0 + f1[1]*w1 + f1[2]*w2 + f1[3]*w3;
            a2 += f2[0]*w0 + f2[1]*w1 + f2[2]*w2 + f2[3]*w3;
            a3 += f3[0]*w0 + f3[1]*w1 + f3[2]*w2 + f3[3]*w3;
        }
        *(f32x4*)&s_r2[ks * 512 + (rg     ) * 16 + c4g * 4] = a0;
        *(f32x4*)&s_r2[ks * 512 + (rg +  8) * 16 + c4g * 4] = a1;
        *(f32x4*)&s_r2[ks * 512 + (rg + 16) * 16 + c4g * 4] = a2;
        *(f32x4*)&s_r2[ks * 512 + (rg + 24) * 16 + c4g * 4] = a3;
        __syncthreads();
        #pragma unroll
        for (int o = 0; o < 2; ++o) {
            int outi = t * 2 + o;
            float s = 0.f;
            #pragma unroll
            for (int p = 0; p < 8; ++p) s += s_r2[p * 512 + outi];
            int r = outi >> 4, cl = outi & 15;
            int col = ct * 16 + cl;
            cstf(h1 + ((size_t)e * NB + r) * D2 + col,
                 gelu_exact(s + b1[e * D2 + col]));
        }
    }
    post_slot(slot2, tb + 3u);

    if (bid >= 128) {                 // no P3/P4 work: arrive at slot3 and exit
        post_slot(slot3, tb + 4u);
        return;
    }

    // prefetch this block's W2 tile during the barrier window
    {
        int e = bid >> 4, ct = bid & 15;
        float* s_w = smem + S_W;
        const float* Wb = W2 + (size_t)e * D2 * HD + ct * 16;
        #pragma unroll
        for (int j = 0; j < 8; ++j) {
            int q = t + j * 256;
            int k = q >> 2, c4 = (q & 3) * 4;
            *(float4*)&s_w[k * 16 + c4] = *(const float4*)(Wb + (size_t)k * HD + c4);
        }
    }
    finish_full(slot2, gen + 1, tb + 3u);

    // ------- P3: eo = h1 @ W2[e] + b2[e] (ks=8, 4r x 4c tile) -----------------
    {
        int e = bid >> 4, ct = bid & 15;
        float* s_f  = smem + S_F;
        float* s_w  = smem + S_W;
        float* s_r2 = smem + S_R2;
        stage16k(h1 + (size_t)e * NB * D2, s_f, t);
        __syncthreads();
        int ks = t >> 5, l = t & 31;
        int rg = l >> 2, c4g = l & 3;
        const float* wb = s_w + c4g * 4;
        int k0 = ks * 64;
        f32x4 a0 = {0.f,0.f,0.f,0.f}, a1 = a0, a2 = a0, a3 = a0;
        #pragma unroll 2
        for (int kq = 0; kq < 16; ++kq) {
            int k = k0 + kq * 4;
            f32x4 w0 = *(const f32x4*)&wb[(k + 0) * 16];
            f32x4 w1 = *(const f32x4*)&wb[(k + 1) * 16];
            f32x4 w2 = *(const f32x4*)&wb[(k + 2) * 16];
            f32x4 w3 = *(const f32x4*)&wb[(k + 3) * 16];
            f32x4 f0 = *(const f32x4*)&s_f[(rg     ) * SFP + k];
            f32x4 f1 = *(const f32x4*)&s_f[(rg +  8) * SFP + k];
            f32x4 f2 = *(const f32x4*)&s_f[(rg + 16) * SFP + k];
            f32x4 f3 = *(const f32x4*)&s_f[(rg + 24) * SFP + k];
            a0 += f0[0]*w0 + f0[1]*w1 + f0[2]*w2 + f0[3]*w3;
            a1 += f1[0]*w0 + f1[1]*w1 + f1[2]*w2 + f1[3]*w3;
            a2 += f2[0]*w0 + f2[1]*w1 + f2[2]*w2 + f2[3]*w3;
            a3 += f3[0]*w0 + f3[1]*w1 + f3[2]*w2 + f3[3]*w3;
        }
        *(f32x4*)&s_r2[ks * 512 + (rg     ) * 16 + c4g * 4] = a0;
        *(f32x4*)&s_r2[ks * 512 + (rg +  8) * 16 + c4g * 4] = a1;
        *(f32x4*)&s_r2[ks * 512 + (rg + 16) * 16 + c4g * 4] = a2;
        *(f32x4*)&s_r2[ks * 512 + (rg + 24) * 16 + c4g * 4] = a3;
        __syncthreads();
        #pragma unroll
        for (int o = 0; o < 2; ++o) {
            int outi = t * 2 + o;
            float s = 0.f;
            #pragma unroll
            for (int p = 0; p < 8; ++p) s += s_r2[p * 512 + outi];
            int r = outi >> 4, cl = outi & 15;
            int col = ct * 16 + cl;
            cstf(eo + ((size_t)e * NB + r) * HD + col, s + b2[e * HD + col]);
        }
    }
    post_slot(slot3, tb + 4u);
    if (bid >= NB) return;            // only 32 blocks do P4

    finish_full(slot3, gen + 2, tb + 4u);

    // ---------------- P4: gather/combine, LN, classifier, aux (32 blocks) -----
    {
        int b = bid;
        float* s_red = smem + S_RED;
        float* s_stats = smem + S_SMALL;
        int e0 = cldi(sel + b * 2 + 0), e1 = cldi(sel + b * 2 + 1);
        float p0 = cldf(pn + b * 2 + 0), p1 = cldf(pn + b * 2 + 1);
        float moe = p0 * cldf(eo + ((size_t)e0 * NB + b) * HD + t)
                  + p1 * cldf(eo + ((size_t)e1 * NB + b) * HD + t);

        s_red[t] = moe; __syncthreads();
        for (int off = 128; off > 0; off >>= 1) {
            if (t < off) s_red[t] += s_red[t + off];
            __syncthreads();
        }
        if (t == 0) s_stats[0] = s_red[0] * (1.f / HD);
        __syncthreads();
        float mu = s_stats[0];
        float d = moe - mu;

        s_red[t] = d * d; __syncthreads();
        for (int off = 128; off > 0; off >>= 1) {
            if (t < off) s_red[t] += s_red[t + off];
            __syncthreads();
        }
        if (t == 0) s_stats[1] = s_red[0] * (1.f / HD);
        __syncthreads();

        float xn = d * rsqrtf(s_stats[1] + 1e-5f);
        float y = fmaf(xn, lng[t], lnb[t]);

        s_red[t] = y * clsW[t * 2 + 0]; __syncthreads();
        for (int off = 128; off > 0; off >>= 1) {
            if (t < off) s_red[t] += s_red[t + off];
            __syncthreads();
        }
        if (t == 0) s_stats[2] = s_red[0] + clsb[0];
        __syncthreads();

        s_red[t] = y * clsW[t * 2 + 1]; __syncthreads();
        for (int off = 128; off > 0; off >>= 1) {
            if (t < off) s_red[t] += s_red[t + off];
            __syncthreads();
        }
        if (t == 0) {
            out[b * 2 + 0] = s_stats[2];
            out[b * 2 + 1] = s_red[0] + clsb[1];
        }

        if (bid == 0) {
            __syncthreads();
            s_red[t] = cldf(probs + t);
            __syncthreads();
            for (int off = 128; off >= 8; off >>= 1) {
                if (t < off) s_red[t] += s_red[t + off];
                __syncthreads();
            }
            if (t == 0) {
                float aux = 0.f;
                for (int e = 0; e < NE; ++e) {
                    float u = s_red[e] * (1.f / 32.f);
                    aux += u * logf(0.125f) - logf(u) * 0.125f;
                }
                out[64] = 0.1f * aux;
            }
        }
    }

    // LC bump: block 0 published gen[2] only after all 256 slot3 posts, so
    // every block has long passed its LC read -> race-free.
    if (bid == 0 && t == 0)
        __hip_atomic_store(LC, s_lc + 1u, __ATOMIC_RELAXED,
                           __HIP_MEMORY_SCOPE_AGENT);
}

extern "C" void kernel_launch(void* const* d_in, const int* in_sizes, int n_in,
                              void* d_out, int out_size, void* d_ws, size_t ws_size,
                              hipStream_t stream) {
    (void)in_sizes; (void)n_in; (void)out_size; (void)ws_size;
    const float* smiles = (const float*)d_in[2];
    const float* sW  = (const float*)d_in[7];
    const float* sb  = (const float*)d_in[8];
    const float* Wv  = (const float*)d_in[13];
    const float* bv  = (const float*)d_in[14];
    const float* Wo  = (const float*)d_in[15];
    const float* bo  = (const float*)d_in[16];
    const float* gW  = (const float*)d_in[17];
    const float* gb  = (const float*)d_in[18];
    const float* W1  = (const float*)d_in[19];
    const float* b1  = (const float*)d_in[20];
    const float* W2  = (const float*)d_in[21];
    const float* b2  = (const float*)d_in[22];
    const float* lng = (const float*)d_in[23];
    const float* lnb = (const float*)d_in[24];
    const float* cW  = (const float*)d_in[25];
    const float* cb  = (const float*)d_in[26];
    float* out = (float*)d_out;
    float* ws  = (float*)d_ws;

    float*    proj  = ws;                      // 8192
    float*    fused = ws + 8192;               // 16384
    float*    probs = ws + 24576;              // 256
    float*    pn    = ws + 24832;              // 64
    int*      sel   = (int*)(ws + 24896);      // 64
    float*    h1    = ws + 24960;              // 131072
    float*    eo    = ws + 156032;             // 65536
    unsigned* slot0 = (unsigned*)(ws + 221568);// 256
    unsigned* slot1 = (unsigned*)(ws + 221824);// 256
    unsigned* slot2 = (unsigned*)(ws + 222080);// 256
    unsigned* slot3 = (unsigned*)(ws + 222336);// 256
    unsigned* gen   = (unsigned*)(ws + 222592);// 4
    unsigned* LC    = (unsigned*)(ws + 222596);// 1

    fused_all<<<NBLK, NTHR, 0, stream>>>(
        smiles, sW, sb, Wv, bv, Wo, bo, gW, gb, W1, b1, W2, b2,
        lng, lnb, cW, cb,
        proj, fused, probs, pn, sel, h1, eo,
        slot0, slot1, slot2, slot3, gen, LC, out);
}

// Round 12
// 37.874 us; speedup vs baseline: 1.2680x; 1.0249x over previous
//
#include <hip/hip_runtime.h>
#include <math.h>

#define HD 256
#define SD 768
#define D2 512
#define NE 8
#define NB 32
#define NBLK 256
#define NTHR 256
#define SFP 516   // padded row stride for [32][512] staging

typedef float f32x4 __attribute__((ext_vector_type(4)));
typedef unsigned u32x4 __attribute__((ext_vector_type(4)));

__device__ __forceinline__ float gelu_exact(float x) {
    return 0.5f * x * (1.0f + erff(x * 0.70710678118654752f));
}

// ---- Coherent (L2-bypassing) access for cross-block intermediates ----------
__device__ __forceinline__ void cstf(float* p, float v) {
    __hip_atomic_store(p, v, __ATOMIC_RELAXED, __HIP_MEMORY_SCOPE_AGENT);
}
__device__ __forceinline__ float cldf(const float* p) {
    return __hip_atomic_load(p, __ATOMIC_RELAXED, __HIP_MEMORY_SCOPE_AGENT);
}
__device__ __forceinline__ void csti(int* p, int v) {
    __hip_atomic_store(p, v, __ATOMIC_RELAXED, __HIP_MEMORY_SCOPE_AGENT);
}
__device__ __forceinline__ int cldi(const int* p) {
    return __hip_atomic_load(p, __ATOMIC_RELAXED, __HIP_MEMORY_SCOPE_AGENT);
}

// Bulk-stage 64KB global->LDS ([32][SFP]), 16 pipelined coherent dwordx4
// loads, one vmcnt drain, LDS float4 writes (R6, verified).
__device__ __forceinline__ void stage16k(const float* __restrict__ gsrc,
                                         float* __restrict__ lds, int t)
{
    const f32x4* src = (const f32x4*)gsrc;
    f32x4 r[16];
    #pragma unroll
    for (int j = 0; j < 16; ++j) {
        const f32x4* p = src + (t + j * 256);
        asm volatile("global_load_dwordx4 %0, %1, off sc0 sc1"
                     : "=v"(r[j]) : "v"(p));
    }
    asm volatile("s_waitcnt vmcnt(0)" ::: "memory");
    __builtin_amdgcn_sched_barrier(0);
    #pragma unroll
    for (int j = 0; j < 16; ++j) {
        int q = t + j * 256;
        *(f32x4*)&lds[(q >> 7) * SFP + (q & 127) * 4] = r[j];
    }
}

// ---- Sync primitives -------------------------------------------------------
// post_slot: __syncthreads drains vmcnt (sc1 stores at L3), thread0 publishes.
__device__ __forceinline__ void post_slot(unsigned* slots, unsigned tok) {
    __syncthreads();
    if (threadIdx.x == 0)
        __hip_atomic_store(slots + blockIdx.x, tok, __ATOMIC_RELAXED,
                           __HIP_MEMORY_SCOPE_AGENT);
}

// Hierarchical finish (for barriers with ~256 waiters): block0 scans,
// publishes gen; others poll one word. (R8/R11, verified)
__device__ __forceinline__ void finish_full(const unsigned* slots,
                                            unsigned* gen, unsigned tok) {
    const int t = threadIdx.x;
    if (blockIdx.x == 0) {
        if (t < 64) {
            const u32x4* p = (const u32x4*)slots + t;
            for (;;) {
                u32x4 v;
                asm volatile("global_load_dwordx4 %0, %1, off sc0 sc1\n\t"
                             "s_waitcnt vmcnt(0)"
                             : "=&v"(v) : "v"(p) : "memory");
                bool ok = (v[0] == tok) & (v[1] == tok) &
                          (v[2] == tok) & (v[3] == tok);
                if (__ballot(ok) == ~0ull) break;
                __builtin_amdgcn_s_sleep(1);
            }
            if (t == 0)
                __hip_atomic_store(gen, tok, __ATOMIC_RELAXED,
                                   __HIP_MEMORY_SCOPE_AGENT);
        }
    } else {
        if (t == 0) {
            while (__hip_atomic_load(gen, __ATOMIC_RELAXED,
                                     __HIP_MEMORY_SCOPE_AGENT) != tok)
                __builtin_amdgcn_s_sleep(1);
        }
    }
    __builtin_amdgcn_fence(__ATOMIC_ACQUIRE, "workgroup");
    __syncthreads();
}

// Direct subset wait (for small waiter sets — R10 lesson: safe when
// pollers-per-line is small). Lane q polls quad q of the slot window.
__device__ __forceinline__ void wait_subset(const unsigned* slots, int nq,
                                            unsigned tok) {
    if ((int)threadIdx.x < nq) {
        const u32x4* p = (const u32x4*)slots + threadIdx.x;
        for (;;) {
            u32x4 v;
            asm volatile("global_load_dwordx4 %0, %1, off sc0 sc1\n\t"
                         "s_waitcnt vmcnt(0)"
                         : "=&v"(v) : "v"(p) : "memory");
            if ((v[0] == tok) & (v[1] == tok) & (v[2] == tok) & (v[3] == tok))
                break;
            __builtin_amdgcn_s_sleep(2);
        }
    }
    __builtin_amdgcn_fence(__ATOMIC_ACQUIRE, "workgroup");
    __syncthreads();
}

// Dual-expert wait: lanes 0-3 poll expert ea's 4 quads, lanes 4-7 expert eb's.
__device__ __forceinline__ void wait_two_experts(const unsigned* slots,
                                                 int ea, int eb, unsigned tok) {
    if (threadIdx.x < 8) {
        int es = (threadIdx.x < 4) ? ea : eb;
        const u32x4* p = (const u32x4*)slots + es * 4 + (threadIdx.x & 3);
        for (;;) {
            u32x4 v;
            asm volatile("global_load_dwordx4 %0, %1, off sc0 sc1\n\t"
                         "s_waitcnt vmcnt(0)"
                         : "=&v"(v) : "v"(p) : "memory");
            if ((v[0] == tok) & (v[1] == tok) & (v[2] == tok) & (v[3] == tok))
                break;
            __builtin_amdgcn_s_sleep(2);
        }
    }
    __builtin_amdgcn_fence(__ATOMIC_ACQUIRE, "workgroup");
    __syncthreads();
}

// Shared-memory carve-up (floats)
#define S_F     0                    // 32*516 = 16512
#define S_W     16512                // 512*16 = 8192
#define S_R2    (16512 + 8192)       // 8*512 = 4096 (k-split partials; P1 s_acc)
#define S_RED   (16512 + 8192 + 4096)        // 256
#define S_SMALL (16512 + 8192 + 4096 + 256)  // 16
#define SMEM_F  (16512 + 8192 + 4096 + 256 + 16)   // 116,288 B

__global__ __launch_bounds__(256) void fused_all(
    const float* __restrict__ smiles,
    const float* __restrict__ sW, const float* __restrict__ sb,
    const float* __restrict__ Wv, const float* __restrict__ bv,
    const float* __restrict__ Wo, const float* __restrict__ bo,
    const float* __restrict__ gW, const float* __restrict__ gb,
    const float* __restrict__ W1, const float* __restrict__ b1,
    const float* __restrict__ W2, const float* __restrict__ b2,
    const float* __restrict__ lng, const float* __restrict__ lnb,
    const float* __restrict__ clsW, const float* __restrict__ clsb,
    float* __restrict__ proj, float* __restrict__ fused,
    float* __restrict__ probs, float* __restrict__ pn,
    int* __restrict__ sel, float* __restrict__ h1,
    float* __restrict__ eo,
    unsigned* __restrict__ slot0, unsigned* __restrict__ slot1,
    unsigned* __restrict__ slot2, unsigned* __restrict__ slot3,
    unsigned* __restrict__ gen, unsigned* __restrict__ LC,
    float* __restrict__ out)
{
    __shared__ __align__(16) float smem[SMEM_F];
    __shared__ unsigned s_lc;
    const int bid = blockIdx.x, t = threadIdx.x;

    if (t == 0)
        s_lc = __hip_atomic_load(LC, __ATOMIC_RELAXED, __HIP_MEMORY_SCOPE_AGENT);
    __syncthreads();
    const unsigned tb = s_lc * 2654435761u;

    // ---------------- P0: proj = smiles @ sW + sb (256 blocks) ----------------
    {
        int r = bid >> 3, sl = bid & 7;
        float* s_in = smem + S_F;                   // 768
        float* s_red = smem + S_RED;
        const float* srow = smiles + (size_t)r * SD;
        for (int i = t; i < SD / 4; i += NTHR)
            ((float4*)s_in)[i] = ((const float4*)srow)[i];
        __syncthreads();
        int c = t & 31, kq = t >> 5;                // 32 cols x 8 k-quadrants
        float acc = 0.f;
        const float* wp = sW + (size_t)(kq * 96) * HD + sl * 32 + c;
        #pragma unroll 8
        for (int k = 0; k < 96; ++k)
            acc = fmaf(s_in[kq * 96 + k], wp[(size_t)k * HD], acc);
        s_red[t] = acc;
        __syncthreads();
        if (t < 32) {
            float s = 0.f;
            #pragma unroll
            for (int q = 0; q < 8; ++q) s += s_red[q * 32 + t];
            int col = sl * 32 + t;
            s += sb[col];
            cstf(proj + r * HD + col, s);
            cstf(fused + (size_t)r * 2 * HD + HD + col, s);   // 2nd half = proj
        }
    }
    post_slot(slot0, tb + 1u);

    // ---------------- P1: v -> attended -> gate/top2 (32 blocks) --------------
    if (bid < NB) {
        wait_subset(slot0 + bid * 8, 2, tb + 1u);   // this row's 8 P0 producers
        int b = bid;
        float* s_p   = smem + S_F;           // 256
        float* s_v   = smem + S_F + 256;     // 256
        float* s_f2  = smem + S_F + 512;     // 512
        float* s_acc = smem + S_R2;          // 1024
        float* s_red = smem + S_RED;
        float* s_gate = smem + S_SMALL;
        s_p[t] = cldf(proj + b * HD + t);
        __syncthreads();
        int ks = t >> 6, cg = t & 63;        // 4 k-splits x 64 col-quads

        f32x4 av = {0.f, 0.f, 0.f, 0.f};
        #pragma unroll 16
        for (int kk = 0; kk < 64; ++kk) {
            int k = ks * 64 + kk;
            f32x4 w = *(const f32x4*)(Wv + (size_t)k * HD + cg * 4);
            av += s_p[k] * w;
        }
        *(f32x4*)&s_acc[ks * 256 + cg * 4] = av;
        __syncthreads();
        s_v[t] = s_acc[t] + s_acc[256 + t] + s_acc[512 + t] + s_acc[768 + t]
               + bv[t];
        __syncthreads();

        f32x4 ao = {0.f, 0.f, 0.f, 0.f};
        #pragma unroll 16
        for (int kk = 0; kk < 64; ++kk) {
            int k = ks * 64 + kk;
            f32x4 w = *(const f32x4*)(Wo + (size_t)k * HD + cg * 4);
            ao += s_v[k] * w;
        }
        *(f32x4*)&s_acc[ks * 256 + cg * 4] = ao;
        __syncthreads();
        float att = s_acc[t] + s_acc[256 + t] + s_acc[512 + t] + s_acc[768 + t]
                  + bo[t];
        s_f2[t] = att;
        s_f2[HD + t] = s_p[t];
        cstf(fused + (size_t)b * 2 * HD + t, att);
        __syncthreads();

        int e = t & 7, ch = t >> 3;
        float gp = 0.f;
        #pragma unroll
        for (int j = 0; j < 16; ++j) {
            int d = ch * 16 + j;
            gp = fmaf(s_f2[d], gW[d * NE + e], gp);
        }
        s_red[t] = gp;
        __syncthreads();
        for (int off = 128; off >= 8; off >>= 1) {
            if (t < off) s_red[t] += s_red[t + off];
            __syncthreads();
        }
        if (t < NE) s_gate[t] = s_red[t] + gb[t];
        __syncthreads();
        if (t == 0) {
            float m = s_gate[0];
            for (int i = 1; i < NE; ++i) m = fmaxf(m, s_gate[i]);
            float ex[NE], ssum = 0.f;
            for (int i = 0; i < NE; ++i) { ex[i] = expf(s_gate[i] - m); ssum += ex[i]; }
            float pr[NE];
            for (int i = 0; i < NE; ++i) { pr[i] = ex[i] / ssum; cstf(probs + b * NE + i, pr[i]); }
            int i1 = 0;
            for (int i = 1; i < NE; ++i) if (pr[i] > pr[i1]) i1 = i;
            int i2 = (i1 == 0) ? 1 : 0;
            for (int i = 0; i < NE; ++i) if (i != i1 && pr[i] > pr[i2]) i2 = i;
            float p1 = pr[i1], p2 = pr[i2], s12 = p1 + p2;
            csti(sel + b * 2 + 0, i1);
            csti(sel + b * 2 + 1, i2);
            cstf(pn + b * 2 + 0, p1 / s12);
            cstf(pn + b * 2 + 1, p2 / s12);
        }
    }
    post_slot(slot1, tb + 2u);

    // prefetch this block's W1 tile into LDS during the barrier window
    {
        int e = bid >> 5, ct = bid & 31;
        float* s_w = smem + S_W;
        const float* Wb = W1 + (size_t)e * D2 * D2 + ct * 16;
        #pragma unroll
        for (int j = 0; j < 8; ++j) {
            int q = t + j * 256;
            int k = q >> 2, c4 = (q & 3) * 4;
            *(float4*)&s_w[k * 16 + c4] = *(const float4*)(Wb + (size_t)k * D2 + c4);
        }
    }
    finish_full(slot1, gen + 0, tb + 2u);   // P1 -> P2: 256 waiters, hierarchical

    // ------- P2: h1 = gelu(fused @ W1[e] + b1[e]) (ks=8, 4r x 4c tile) --------
    {
        int e = bid >> 5, ct = bid & 31;
        float* s_f  = smem + S_F;
        float* s_w  = smem + S_W;
        float* s_r2 = smem + S_R2;   // [8 ks][512 outs]
        stage16k(fused, s_f, t);
        __syncthreads();
        int ks = t >> 5, l = t & 31;
        int rg = l >> 2, c4g = l & 3;
        const float* wb = s_w + c4g * 4;
        int k0 = ks * 64;
        f32x4 a0 = {0.f,0.f,0.f,0.f}, a1 = a0, a2 = a0, a3 = a0;
        #pragma unroll 2
        for (int kq = 0; kq < 16; ++kq) {
            int k = k0 + kq * 4;
            f32x4 w0 = *(const f32x4*)&wb[(k + 0) * 16];
            f32x4 w1 = *(const f32x4*)&wb[(k + 1) * 16];
            f32x4 w2 = *(const f32x4*)&wb[(k + 2) * 16];
            f32x4 w3 = *(const f32x4*)&wb[(k + 3) * 16];
            f32x4 f0 = *(const f32x4*)&s_f[(rg     ) * SFP + k];
            f32x4 f1 = *(const f32x4*)&s_f[(rg +  8) * SFP + k];
            f32x4 f2 = *(const f32x4*)&s_f[(rg + 16) * SFP + k];
            f32x4 f3 = *(const f32x4*)&s_f[(rg + 24) * SFP + k];
            a0 += f0[0]*w0 + f0[1]*w1 + f0[2]*w2 + f0[3]*w3;
            a1 += f1[0]*w0 + f1[1]*w1 + f1[2]*w2 + f1[3]*w3;
            a2 += f2[0]*w0 + f2[1]*w1 + f2[2]*w2 + f2[3]*w3;
            a3 += f3[0]*w0 + f3[1]*w1 + f3[2]*w2 + f3[3]*w3;
        }
        *(f32x4*)&s_r2[ks * 512 + (rg     ) * 16 + c4g * 4] = a0;
        *(f32x4*)&s_r2[ks * 512 + (rg +  8) * 16 + c4g * 4] = a1;
        *(f32x4*)&s_r2[ks * 512 + (rg + 16) * 16 + c4g * 4] = a2;
        *(f32x4*)&s_r2[ks * 512 + (rg + 24) * 16 + c4g * 4] = a3;
        __syncthreads();
        #pragma unroll
        for (int o = 0; o < 2; ++o) {
            int outi = t * 2 + o;
            float s = 0.f;
            #pragma unroll
            for (int p = 0; p < 8; ++p) s += s_r2[p * 512 + outi];
            int r = outi >> 4, cl = outi & 15;
            int col = ct * 16 + cl;
            cstf(h1 + ((size_t)e * NB + r) * D2 + col,
                 gelu_exact(s + b1[e * D2 + col]));
        }
    }
    post_slot(slot2, tb + 3u);
    if (bid >= 128) return;          // done — frees CUs for P3

    // prefetch this block's W2 tile during the wait window
    {
        int e = bid >> 4, ct = bid & 15;
        float* s_w = smem + S_W;
        const float* Wb = W2 + (size_t)e * D2 * HD + ct * 16;
        #pragma unroll
        for (int j = 0; j < 8; ++j) {
            int q = t + j * 256;
            int k = q >> 2, c4 = (q & 3) * 4;
            *(float4*)&s_w[k * 16 + c4] = *(const float4*)(Wb + (size_t)k * HD + c4);
        }
    }
    // P2 -> P3: direct expert-subset wait (this expert's 32 producers; 8 quads,
    // 128 pollers per 2 lines — no herd, and no detect/publish hops)
    {
        int e = bid >> 4;
        wait_subset(slot2 + e * 32, 8, tb + 3u);
    }

    // ------- P3: eo = h1 @ W2[e] + b2[e] (ks=8, 4r x 4c tile) -----------------
    {
        int e = bid >> 4, ct = bid & 15;
        float* s_f  = smem + S_F;
        float* s_w  = smem + S_W;
        float* s_r2 = smem + S_R2;
        stage16k(h1 + (size_t)e * NB * D2, s_f, t);
        __syncthreads();
        int ks = t >> 5, l = t & 31;
        int rg = l >> 2, c4g = l & 3;
        const float* wb = s_w + c4g * 4;
        int k0 = ks * 64;
        f32x4 a0 = {0.f,0.f,0.f,0.f}, a1 = a0, a2 = a0, a3 = a0;
        #pragma unroll 2
        for (int kq = 0; kq < 16; ++kq) {
            int k = k0 + kq * 4;
            f32x4 w0 = *(const f32x4*)&wb[(k + 0) * 16];
            f32x4 w1 = *(const f32x4*)&wb[(k + 1) * 16];
            f32x4 w2 = *(const f32x4*)&wb[(k + 2) * 16];
            f32x4 w3 = *(const f32x4*)&wb[(k + 3) * 16];
            f32x4 f0 = *(const f32x4*)&s_f[(rg     ) * SFP + k];
            f32x4 f1 = *(const f32x4*)&s_f[(rg +  8) * SFP + k];
            f32x4 f2 = *(const f32x4*)&s_f[(rg + 16) * SFP + k];
            f32x4 f3 = *(const f32x4*)&s_f[(rg + 24) * SFP + k];
            a0 += f0[0]*w0 + f0[1]*w1 + f0[2]*w2 + f0[3]*w3;
            a1 += f1[0]*w0 + f1[1]*w1 + f1[2]*w2 + f1[3]*w3;
            a2 += f2[0]*w0 + f2[1]*w1 + f2[2]*w2 + f2[3]*w3;
            a3 += f3[0]*w0 + f3[1]*w1 + f3[2]*w2 + f3[3]*w3;
        }
        *(f32x4*)&s_r2[ks * 512 + (rg     ) * 16 + c4g * 4] = a0;
        *(f32x4*)&s_r2[ks * 512 + (rg +  8) * 16 + c4g * 4] = a1;
        *(f32x4*)&s_r2[ks * 512 + (rg + 16) * 16 + c4g * 4] = a2;
        *(f32x4*)&s_r2[ks * 512 + (rg + 24) * 16 + c4g * 4] = a3;
        __syncthreads();
        #pragma unroll
        for (int o = 0; o < 2; ++o) {
            int outi = t * 2 + o;
            float s = 0.f;
            #pragma unroll
            for (int p = 0; p < 8; ++p) s += s_r2[p * 512 + outi];
            int r = outi >> 4, cl = outi & 15;
            int col = ct * 16 + cl;
            cstf(eo + ((size_t)e * NB + r) * HD + col, s + b2[e * HD + col]);
        }
    }
    post_slot(slot3, tb + 4u);
    if (bid >= NB) return;           // only 32 blocks do P4

    // ---------------- P4: gather/combine, LN, classifier, aux (32 blocks) -----
    {
        int b = bid;
        float* s_red = smem + S_RED;
        float* s_stats = smem + S_SMALL;
        // sel/pn written in P1 — visible since before the P1->P2 full barrier
        int e0 = cldi(sel + b * 2 + 0), e1 = cldi(sel + b * 2 + 1);
        float p0 = cldf(pn + b * 2 + 0), p1 = cldf(pn + b * 2 + 1);

        // P3 -> P4: wait only on the two selected experts' 16 producers each
        wait_two_experts(slot3, e0, e1, tb + 4u);

        float moe = p0 * cldf(eo + ((size_t)e0 * NB + b) * HD + t)
                  + p1 * cldf(eo + ((size_t)e1 * NB + b) * HD + t);

        s_red[t] = moe; __syncthreads();
        for (int off = 128; off > 0; off >>= 1) {
            if (t < off) s_red[t] += s_red[t + off];
            __syncthreads();
        }
        if (t == 0) s_stats[0] = s_red[0] * (1.f / HD);
        __syncthreads();
        float mu = s_stats[0];
        float d = moe - mu;

        s_red[t] = d * d; __syncthreads();
        for (int off = 128; off > 0; off >>= 1) {
            if (t < off) s_red[t] += s_red[t + off];
            __syncthreads();
        }
        if (t == 0) s_stats[1] = s_red[0] * (1.f / HD);
        __syncthreads();

        float xn = d * rsqrtf(s_stats[1] + 1e-5f);
        float y = fmaf(xn, lng[t], lnb[t]);

        s_red[t] = y * clsW[t * 2 + 0]; __syncthreads();
        for (int off = 128; off > 0; off >>= 1) {
            if (t < off) s_red[t] += s_red[t + off];
            __syncthreads();
        }
        if (t == 0) s_stats[2] = s_red[0] + clsb[0];
        __syncthreads();

        s_red[t] = y * clsW[t * 2 + 1]; __syncthreads();
        for (int off = 128; off > 0; off >>= 1) {
            if (t < off) s_red[t] += s_red[t + off];
            __syncthreads();
        }
        if (t == 0) {
            out[b * 2 + 0] = s_stats[2];
            out[b * 2 + 1] = s_red[0] + clsb[1];
        }

        if (bid == 0) {
            __syncthreads();
            s_red[t] = cldf(probs + t);
            __syncthreads();
            for (int off = 128; off >= 8; off >>= 1) {
                if (t < off) s_red[t] += s_red[t + off];
                __syncthreads();
            }
            if (t == 0) {
                float aux = 0.f;
                for (int e = 0; e < NE; ++e) {
                    float u = s_red[e] * (1.f / 32.f);
                    aux += u * logf(0.125f) - logf(u) * 0.125f;
                }
                out[64] = 0.1f * aux;
            }
        }
    }

    // LC bump: block 0 first verifies all 256 blocks posted slot2 (i.e. they
    // all long since read LC) — one instant poll round — then bumps.
    if (bid == 0) {
        wait_subset(slot2, 64, tb + 3u);
        if (t == 0)
            __hip_atomic_store(LC, s_lc + 1u, __ATOMIC_RELAXED,
                               __HIP_MEMORY_SCOPE_AGENT);
    }
}

extern "C" void kernel_launch(void* const* d_in, const int* in_sizes, int n_in,
                              void* d_out, int out_size, void* d_ws, size_t ws_size,
                              hipStream_t stream) {
    (void)in_sizes; (void)n_in; (void)out_size; (void)ws_size;
    const float* smiles = (const float*)d_in[2];
    const float* sW  = (const float*)d_in[7];
    const float* sb  = (const float*)d_in[8];
    const float* Wv  = (const float*)d_in[13];
    const float* bv  = (const float*)d_in[14];
    const float* Wo  = (const float*)d_in[15];
    const float* bo  = (const float*)d_in[16];
    const float* gW  = (const float*)d_in[17];
    const float* gb  = (const float*)d_in[18];
    const float* W1  = (const float*)d_in[19];
    const float* b1  = (const float*)d_in[20];
    const float* W2  = (const float*)d_in[21];
    const float* b2  = (const float*)d_in[22];
    const float* lng = (const float*)d_in[23];
    const float* lnb = (const float*)d_in[24];
    const float* cW  = (const float*)d_in[25];
    const float* cb  = (const float*)d_in[26];
    float* out = (float*)d_out;
    float* ws  = (float*)d_ws;

    float*    proj  = ws;                      // 8192
    float*    fused = ws + 8192;               // 16384
    float*    probs = ws + 24576;              // 256
    float*    pn    = ws + 24832;              // 64
    int*      sel   = (int*)(ws + 24896);      // 64
    float*    h1    = ws + 24960;              // 131072
    float*    eo    = ws + 156032;             // 65536
    unsigned* slot0 = (unsigned*)(ws + 221568);// 256
    unsigned* slot1 = (unsigned*)(ws + 221824);// 256
    unsigned* slot2 = (unsigned*)(ws + 222080);// 256
    unsigned* slot3 = (unsigned*)(ws + 222336);// 128 (16 per expert)
    unsigned* gen   = (unsigned*)(ws + 222592);// 4
    unsigned* LC    = (unsigned*)(ws + 222596);// 1

    fused_all<<<NBLK, NTHR, 0, stream>>>(
        smiles, sW, sb, Wv, bv, Wo, bo, gW, gb, W1, b1, W2, b2,
        lng, lnb, cW, cb,
        proj, fused, probs, pn, sel, h1, eo,
        slot0, slot1, slot2, slot3, gen, LC, out);
}